// Round 5
// baseline (362.205 us; speedup 1.0000x reference)
//
#include <hip/hip_runtime.h>
#include <math.h>

// TreeBackbone fused — round 5 = round 4 minus the register clamp.
//  round 4's __launch_bounds__(320,4) forced VGPR=64 -> p[28]+acc[16] spilled to
//  scratch (WRITE_SIZE 5.4->77MB). One change: (320,2) so the allocator is free.
//  conv: round-2 pattern (interleaved s_x rows stride 36 -> conflict-free b128).
//  tree: thread=(gh,f) keeps 28 pool floats + all 16 'o' accs in registers;
//        weights bf16 transposed chunk[k][t] uint4 -> fully coalesced L2 streams.
//  reduce over f via LDS stride-9 (odd), two o-halves overlaid on dead s_x.

#define BLOCK 320
#define TREE_T 315
#define NCHUNK 56                                   // uint4 chunks per tree thread
#define TW2_USHORTS (TREE_T * NCHUNK * 8)           // 141120 bf16 = 282240 B

__device__ __forceinline__ float sigmoidf_(float v) {
    return 1.0f / (1.0f + __expf(-v));
}

// tw fp32 (o,f,g,h,w,i,j) -> bf16 chunks [k][t][8]; element e=8k+j of thread t's
// 448-long stream; e -> (o = e/28, widx = e%28), widx = i*14 + 2w + j (pool order).
__global__ __launch_bounds__(256) void prep_tw_bf16(
    const float* __restrict__ tw, ushort* __restrict__ tw2)
{
    int i = blockIdx.x * 256 + threadIdx.x;
    if (i >= TW2_USHORTS) return;
    const int j  = i & 7;
    const int t  = (i >> 3) % TREE_T;
    const int k  = (i >> 3) / TREE_T;
    const int e  = k * 8 + j;                       // 0..447
    const int o  = e / 28, widx = e % 28;
    const int i2 = widx / 14, rem = widx % 14, w = rem >> 1, jj = rem & 1;
    const int f  = t % 15, gh = t / 15, g = gh / 7, h = gh % 7;
    const float v = tw[o * 8820 + f * 588 + g * 196 + h * 28 + w * 4 + i2 * 2 + jj];
    unsigned bb = __float_as_uint(v);
    bb += 0x7fffu + ((bb >> 16) & 1u);              // RNE to bf16
    tw2[i] = (ushort)(bb >> 16);
}

template<int H>
__device__ __forceinline__ void conv_half(
    const float* sx,          // s_x + g*1152 : [32 phys rows][36]
    const float* wrow,        // s_cw + c*25
    float cbias, int py,
    float* pooldst)           // s_pool + c*196 + py*14 + 7*H
{
    float aA[14], aB[14];
    #pragma unroll
    for (int d = 0; d < 14; ++d) { aA[d] = 0.f; aB[d] = 0.f; }
    #pragma unroll
    for (int dr = 0; dr < 6; ++dr) {
        const float* rp = sx + (((dr & 1) << 4) + py + (dr >> 1)) * 36 + 12 * H;
        float f[20];
        #pragma unroll
        for (int k = 0; k < 5; ++k)
            *(float4*)&f[4 * k] = *(const float4*)&rp[4 * k];
        if (dr <= 4) {
            #pragma unroll
            for (int kx = 0; kx < 5; ++kx) {
                const float w = wrow[dr * 5 + kx];
                #pragma unroll
                for (int d = 0; d < 14; ++d) aA[d] += f[d + kx + 2 * H] * w;
            }
        }
        if (dr >= 1) {
            #pragma unroll
            for (int kx = 0; kx < 5; ++kx) {
                const float w = wrow[(dr - 1) * 5 + kx];
                #pragma unroll
                for (int d = 0; d < 14; ++d) aB[d] += f[d + kx + 2 * H] * w;
            }
        }
    }
    #pragma unroll
    for (int p = 0; p < 7; ++p) {
        float m = fmaxf(fmaxf(aA[2 * p], aA[2 * p + 1]),
                        fmaxf(aB[2 * p], aB[2 * p + 1]));
        pooldst[p] = sigmoidf_(m + cbias);
    }
}

template<int USE_BF16>
__global__ __launch_bounds__(BLOCK, 2) void tree_backbone_fused(
    const float* __restrict__ x,    // (B,3,32,32)
    const float* __restrict__ cw,   // (45,25)
    const float* __restrict__ cb,   // (45,)
    const float* __restrict__ tw,   // fp32 fallback
    const uint4* __restrict__ tw2,  // bf16 chunks [56][315]
    const float* __restrict__ tb,   // (336,)
    float* __restrict__ out,        // (B,336)
    int B)
{
    __shared__ float s_pool[45 * 196];              // 35280 B, [c][py*14+px]
    __shared__ float s_cb[45];                      // 180 B
    __shared__ __align__(16) char s_mix[18336];     // conv: s_x(13824)+s_cw(4500); tree: s_part(11340)
    float* s_x    = (float*)s_mix;                  // [3][32 interleaved][36]
    float* s_cw   = (float*)(s_mix + 13824);        // [45][25] flat
    float* s_part = (float*)s_mix;                  // [315][9]

    const int b = blockIdx.x;
    if (b >= B) return;
    const int t = threadIdx.x;

    // ---- stage image, interleaved rows p(r)=16(r&1)+(r>>1) ----
    {
        const float4* xs = (const float4*)(x + (size_t)b * 3072);
        for (int i = t; i < 768; i += BLOCK) {
            const float4 v = xs[i];
            const int g = i >> 8, rem = i & 255, r = rem >> 3, q = rem & 7;
            const int p = ((r & 1) << 4) + (r >> 1);
            *(float4*)&s_x[(g * 32 + p) * 36 + q * 4] = v;
        }
    }
    for (int i = t; i < 1125; i += BLOCK) s_cw[i] = cw[i];
    if (t < 45) s_cb[t] = cb[t];
    __syncthreads();

    // ---- conv + pool + sigmoid: 1260 tasks = (h-major, c, py) ----
    for (int task = t; task < 1260; task += BLOCK) {
        const int h  = (task >= 630) ? 1 : 0;
        const int tt = task - 630 * h;
        const int c  = tt / 14;
        const int py = tt - c * 14;
        const int g  = c / 15;
        float* dst = s_pool + c * 196 + py * 14 + 7 * h;
        if (h == 0) conv_half<0>(s_x + g * 1152, s_cw + c * 25, s_cb[c], py, dst);
        else        conv_half<1>(s_x + g * 1152, s_cw + c * 25, s_cb[c], py, dst);
    }
    __syncthreads();

    // ---- tree partials: thread t<315 = (gh,f); 28 pool floats once, all 16 o ----
    float acc[16];
    #pragma unroll
    for (int o = 0; o < 16; ++o) acc[o] = 0.f;
    if (t < TREE_T) {
        const int f = t % 15, gh = t / 15, g = gh / 7, h = gh % 7;
        const int c = g * 15 + f;
        float p[28];
        #pragma unroll
        for (int k = 0; k < 7; ++k)
            *(float4*)&p[4 * k] = *(const float4*)&s_pool[c * 196 + 28 * h + 4 * k];

        if (USE_BF16) {
            #pragma unroll
            for (int k = 0; k < NCHUNK; ++k) {
                const uint4 u = tw2[k * TREE_T + t];       // coalesced across lanes
                const int e0 = k * 8;
                acc[(e0+0)/28] += p[(e0+0)%28] * __uint_as_float(u.x << 16);
                acc[(e0+1)/28] += p[(e0+1)%28] * __uint_as_float(u.x & 0xffff0000u);
                acc[(e0+2)/28] += p[(e0+2)%28] * __uint_as_float(u.y << 16);
                acc[(e0+3)/28] += p[(e0+3)%28] * __uint_as_float(u.y & 0xffff0000u);
                acc[(e0+4)/28] += p[(e0+4)%28] * __uint_as_float(u.z << 16);
                acc[(e0+5)/28] += p[(e0+5)%28] * __uint_as_float(u.z & 0xffff0000u);
                acc[(e0+6)/28] += p[(e0+6)%28] * __uint_as_float(u.w << 16);
                acc[(e0+7)/28] += p[(e0+7)%28] * __uint_as_float(u.w & 0xffff0000u);
            }
        } else {
            const float* wp = tw + f * 588 + g * 196 + h * 28;
            #pragma unroll
            for (int o = 0; o < 16; ++o) {
                const float4* wf = (const float4*)(wp + o * 8820);
                float a = 0.f;
                #pragma unroll
                for (int w2 = 0; w2 < 7; ++w2) {
                    const float4 q = wf[w2];
                    a += p[2*w2]    * q.x + p[2*w2+1]  * q.y
                       + p[14+2*w2]* q.z + p[15+2*w2] * q.w;
                }
                acc[o] = a;
            }
        }
    }

    // ---- reduce over f, two o-halves through s_part[315][9] ----
    if (t < TREE_T) {
        #pragma unroll
        for (int o = 0; o < 8; ++o) s_part[t * 9 + o] = acc[o];
    }
    __syncthreads();
    if (t < 168) {
        const int o = t / 21, gh = t % 21;
        float a = 0.f;
        #pragma unroll
        for (int f = 0; f < 15; ++f) a += s_part[(gh * 15 + f) * 9 + o];
        out[(size_t)b * 336 + t] = sigmoidf_(a + tb[t]);
    }
    __syncthreads();
    if (t < TREE_T) {
        #pragma unroll
        for (int o = 8; o < 16; ++o) s_part[t * 9 + (o - 8)] = acc[o];
    }
    __syncthreads();
    if (t < 168) {
        const int idx = 168 + t;
        const int o = idx / 21, gh = idx % 21;
        float a = 0.f;
        #pragma unroll
        for (int f = 0; f < 15; ++f) a += s_part[(gh * 15 + f) * 9 + (o - 8)];
        out[(size_t)b * 336 + idx] = sigmoidf_(a + tb[idx]);
    }
}

extern "C" void kernel_launch(void* const* d_in, const int* in_sizes, int n_in,
                              void* d_out, int out_size, void* d_ws, size_t ws_size,
                              hipStream_t stream) {
    const float* x  = (const float*)d_in[0];
    const float* cw = (const float*)d_in[1];
    const float* cb = (const float*)d_in[2];
    const float* tw = (const float*)d_in[3];
    const float* tb = (const float*)d_in[4];
    float* out = (float*)d_out;

    const int B = in_sizes[0] / 3072;   // 4096
    const bool bf = ws_size >= (size_t)TW2_USHORTS * sizeof(ushort);
    if (bf) {
        prep_tw_bf16<<<(TW2_USHORTS + 255) / 256, 256, 0, stream>>>(tw, (ushort*)d_ws);
        tree_backbone_fused<1><<<B, BLOCK, 0, stream>>>(
            x, cw, cb, tw, (const uint4*)d_ws, tb, out, B);
    } else {
        tree_backbone_fused<0><<<B, BLOCK, 0, stream>>>(
            x, cw, cb, tw, (const uint4*)d_ws, tb, out, B);
    }
}

// Round 7
// 337.493 us; speedup vs baseline: 1.0732x; 1.0732x over previous
//
#include <hip/hip_runtime.h>
#include <math.h>

// TreeBackbone — round 7 = round 6 with ONE fix: the chunk-pad zeroing loop
// was `if (t < 315)` under BLOCK=256, leaving chunks 256..314 with garbage
// pads -> garbage*0.0 = NaN. Now grid-stride over all 315 chunks.
//
//  A) conv+pool+sigmoid (round-2 conv) -> bf16 pool chunks [c][h][32]
//     (28 payload + 4 zero pad) staged in 20KB LDS, coalesced flush to d_ws.
//  B) tree: lane = image; pool chunks streamed per-lane (full 64B lines),
//     weights bf16 [gh][f][o][32] wave-uniform (broadcast), 16 accs in regs.
//  Fallback (ws too small): round-2 fused kernel (known-good 214us).

#define BLOCK 256
#define NTW   (21 * 15 * 16 * 32)        // 161280 bf16 weights
#define TWBYTES (NTW * 2)                // 322560 B
#define POOL_USH 10080                   // per image: 45 ch * 7 h * 32
#define POOL_BYTES (POOL_USH * 2)        // 20160 B

__device__ __forceinline__ float sigmoidf_(float v) {
    return 1.0f / (1.0f + __expf(-v));
}
__device__ __forceinline__ ushort f2bf(float v) {
    unsigned u = __float_as_uint(v);
    u += 0x7fffu + ((u >> 16) & 1u);     // RNE
    return (ushort)(u >> 16);
}
__device__ __forceinline__ float bflo(unsigned u) { return __uint_as_float(u << 16); }
__device__ __forceinline__ float bfhi(unsigned u) { return __uint_as_float(u & 0xffff0000u); }

// ---- prep: tw fp32 (o,f,g,h,w,i,j) -> bf16 [gh][f][o][32], e = i*14+2w+j, pad e>=28 ----
__global__ __launch_bounds__(256) void prep_tw(
    const float* __restrict__ tw, ushort* __restrict__ tw2)
{
    int i = blockIdx.x * 256 + threadIdx.x;
    if (i >= NTW) return;
    const int e   = i & 31;
    const int o   = (i >> 5) & 15;
    const int fgh = i >> 9;              // gh*15 + f
    const int f   = fgh % 15, gh = fgh / 15;
    const int g   = gh / 7,  h  = gh % 7;
    float v = 0.f;
    if (e < 28) {
        const int i2 = e / 14, rem = e % 14, w = rem >> 1, j = rem & 1;
        v = tw[o * 8820 + f * 588 + g * 196 + h * 28 + w * 4 + i2 * 2 + j];
    }
    tw2[i] = f2bf(v);
}

// ---- conv core (round-2 verbatim, dst is bf16) ----
template<int H>
__device__ __forceinline__ void conv_half(
    const float* sx,          // s_x + g*1152 : [32 phys rows][36]
    const float* wrow,        // s_cw + c*25
    float cbias, int py,
    ushort* pooldst)          // 7 values px = 7H..7H+6, consecutive
{
    float aA[14], aB[14];
    #pragma unroll
    for (int d = 0; d < 14; ++d) { aA[d] = 0.f; aB[d] = 0.f; }
    #pragma unroll
    for (int dr = 0; dr < 6; ++dr) {
        const float* rp = sx + (((dr & 1) << 4) + py + (dr >> 1)) * 36 + 12 * H;
        float f[20];
        #pragma unroll
        for (int k = 0; k < 5; ++k)
            *(float4*)&f[4 * k] = *(const float4*)&rp[4 * k];
        if (dr <= 4) {
            #pragma unroll
            for (int kx = 0; kx < 5; ++kx) {
                const float w = wrow[dr * 5 + kx];
                #pragma unroll
                for (int d = 0; d < 14; ++d) aA[d] += f[d + kx + 2 * H] * w;
            }
        }
        if (dr >= 1) {
            #pragma unroll
            for (int kx = 0; kx < 5; ++kx) {
                const float w = wrow[(dr - 1) * 5 + kx];
                #pragma unroll
                for (int d = 0; d < 14; ++d) aB[d] += f[d + kx + 2 * H] * w;
            }
        }
    }
    #pragma unroll
    for (int p = 0; p < 7; ++p) {
        float m = fmaxf(fmaxf(aA[2 * p], aA[2 * p + 1]),
                        fmaxf(aB[2 * p], aB[2 * p + 1]));
        pooldst[p] = f2bf(sigmoidf_(m + cbias));
    }
}

// ---- kernel A: conv + pool + sigmoid -> bf16 pool chunks in d_ws ----
__global__ __launch_bounds__(BLOCK) void conv_pool_kernel(
    const float* __restrict__ x,    // (B,3,32,32)
    const float* __restrict__ cw,   // (45,25)
    const float* __restrict__ cb,   // (45,)
    ushort* __restrict__ pool16,    // (B, 45*7*32) bf16
    int B)
{
    __shared__ float  s_x[3 * 32 * 36];   // 13824 B interleaved rows
    __shared__ float  s_cw[45 * 25];      // 4500 B
    __shared__ float  s_cb[45];
    __shared__ ushort s_p16[POOL_USH];    // 20160 B

    const int b = blockIdx.x;
    if (b >= B) return;
    const int t = threadIdx.x;

    const float4* xs = (const float4*)(x + (size_t)b * 3072);
    for (int i = t; i < 768; i += BLOCK) {
        const float4 v = xs[i];
        const int g = i >> 8, rem = i & 255, r = rem >> 3, q = rem & 7;
        const int p = ((r & 1) << 4) + (r >> 1);
        *(float4*)&s_x[(g * 32 + p) * 36 + q * 4] = v;
    }
    for (int i = t; i < 1125; i += BLOCK) s_cw[i] = cw[i];
    if (t < 45) s_cb[t] = cb[t];
    for (int i = t; i < 315; i += BLOCK)                       // FIX: grid-stride (was if t<315)
        *(uint2*)&s_p16[i * 32 + 28] = make_uint2(0u, 0u);
    __syncthreads();

    for (int task = t; task < 1260; task += BLOCK) {
        const int h  = (task >= 630) ? 1 : 0;
        const int tt = task - 630 * h;
        const int c  = tt / 14;
        const int py = tt - c * 14;
        const int g  = c / 15;
        // chunk = (c, h_tree=py>>1); within chunk e = (py&1)*14 + px, px = 7h..7h+6
        ushort* dst = s_p16 + (c * 7 + (py >> 1)) * 32 + (py & 1) * 14 + 7 * h;
        if (h == 0) conv_half<0>(s_x + g * 1152, s_cw + c * 25, s_cb[c], py, dst);
        else        conv_half<1>(s_x + g * 1152, s_cw + c * 25, s_cb[c], py, dst);
    }
    __syncthreads();

    const uint4* src = (const uint4*)s_p16;
    uint4* dst = (uint4*)(pool16 + (size_t)b * POOL_USH);
    for (int i = t; i < POOL_USH / 8; i += BLOCK) dst[i] = src[i];
}

// ---- kernel B: tree contraction, lane = image ----
__global__ __launch_bounds__(64) void tree_kernel(
    const ushort* __restrict__ pool16,  // (B, 10080) bf16
    const ushort* __restrict__ tw2,     // [gh][f][o][32] bf16
    const float* __restrict__ tb,       // (336,)
    float* __restrict__ out,            // (B,336)
    int B)
{
    const int gh   = blockIdx.x % 21;
    const int tile = blockIdx.x / 21;
    const int b    = tile * 64 + threadIdx.x;
    if (b >= B) return;
    const int g = gh / 7, h = gh % 7;

    float acc[16];
    #pragma unroll
    for (int o = 0; o < 16; ++o) acc[o] = 0.f;

    const ushort* prow = pool16 + (size_t)b * POOL_USH;
    #pragma unroll 1
    for (int f = 0; f < 15; ++f) {
        const uint4* pc = (const uint4*)(prow + ((g * 15 + f) * 7 + h) * 32);
        const uint4* wc = (const uint4*)(tw2 + (size_t)((gh * 15 + f) * 16) * 32);
        #pragma unroll
        for (int k = 0; k < 4; ++k) {
            const uint4 pu = pc[k];
            float ps[8];
            ps[0] = bflo(pu.x); ps[1] = bfhi(pu.x);
            ps[2] = bflo(pu.y); ps[3] = bfhi(pu.y);
            ps[4] = bflo(pu.z); ps[5] = bfhi(pu.z);
            ps[6] = bflo(pu.w); ps[7] = bfhi(pu.w);
            #pragma unroll
            for (int o = 0; o < 16; ++o) {
                const uint4 wu = wc[o * 4 + k];   // wave-uniform address
                acc[o] += ps[0] * bflo(wu.x) + ps[1] * bfhi(wu.x)
                        + ps[2] * bflo(wu.y) + ps[3] * bfhi(wu.y)
                        + ps[4] * bflo(wu.z) + ps[5] * bfhi(wu.z)
                        + ps[6] * bflo(wu.w) + ps[7] * bfhi(wu.w);
            }
        }
    }
    #pragma unroll
    for (int o = 0; o < 16; ++o) {
        const int idx = o * 21 + gh;
        out[(size_t)b * 336 + idx] = sigmoidf_(acc[o] + tb[idx]);
    }
}

// ---- fallback: round-2 fused kernel verbatim (fp32 tree from global tw) ----
__global__ __launch_bounds__(BLOCK) void tree_backbone_legacy(
    const float* __restrict__ x, const float* __restrict__ cw,
    const float* __restrict__ cb, const float* __restrict__ tw,
    const float* __restrict__ tb, float* __restrict__ out, int B)
{
    __shared__ float s_x[3 * 32 * 36];
    __shared__ float s_cwl[45 * 25];
    __shared__ float s_cb[45];
    __shared__ float s_pool[45][197];

    const int b = blockIdx.x;
    if (b >= B) return;
    const int t = threadIdx.x;

    const float4* xs = (const float4*)(x + (size_t)b * 3072);
    for (int i = t; i < 768; i += BLOCK) {
        const float4 v = xs[i];
        const int g = i >> 8, rem = i & 255, r = rem >> 3, q = rem & 7;
        const int p = ((r & 1) << 4) + (r >> 1);
        *(float4*)&s_x[(g * 32 + p) * 36 + q * 4] = v;
    }
    for (int i = t; i < 1125; i += BLOCK) s_cwl[i] = cw[i];
    if (t < 45) s_cb[t] = cb[t];
    __syncthreads();

    for (int task = t; task < 1260; task += BLOCK) {
        const int h  = (task >= 630) ? 1 : 0;
        const int tt = task - 630 * h;
        const int c  = tt / 14;
        const int py = tt - c * 14;
        const int g  = c / 15;
        float aA[14], aB[14];
        #pragma unroll
        for (int d = 0; d < 14; ++d) { aA[d] = 0.f; aB[d] = 0.f; }
        #pragma unroll
        for (int dr = 0; dr < 6; ++dr) {
            const float* rp = s_x + (g * 32 + ((dr & 1) << 4) + py + (dr >> 1)) * 36 + 12 * h;
            float f[20];
            #pragma unroll
            for (int k = 0; k < 5; ++k)
                *(float4*)&f[4 * k] = *(const float4*)&rp[4 * k];
            if (dr <= 4)
                #pragma unroll
                for (int kx = 0; kx < 5; ++kx) {
                    const float w = s_cwl[c * 25 + dr * 5 + kx];
                    #pragma unroll
                    for (int d = 0; d < 14; ++d) aA[d] += f[d + kx + 2 * h] * w;
                }
            if (dr >= 1)
                #pragma unroll
                for (int kx = 0; kx < 5; ++kx) {
                    const float w = s_cwl[c * 25 + (dr - 1) * 5 + kx];
                    #pragma unroll
                    for (int d = 0; d < 14; ++d) aB[d] += f[d + kx + 2 * h] * w;
                }
        }
        float* dst = &s_pool[c][py * 14 + 7 * h];
        #pragma unroll
        for (int p = 0; p < 7; ++p) {
            float m = fmaxf(fmaxf(aA[2 * p], aA[2 * p + 1]),
                            fmaxf(aB[2 * p], aB[2 * p + 1]));
            dst[p] = sigmoidf_(m + s_cb[c]);
        }
    }
    __syncthreads();

    for (int idx = t; idx < 336; idx += BLOCK) {
        const int o  = idx / 21;
        const int r2 = idx - o * 21;
        const int g  = r2 / 7;
        const int hh = r2 - g * 7;
        const float* wp = tw + o * 8820 + g * 196 + hh * 28;
        float acc = 0.0f;
        #pragma unroll 1
        for (int f = 0; f < 15; ++f) {
            const float4* wf = (const float4*)(wp + f * 588);
            const float* p0 = &s_pool[g * 15 + f][(2 * hh) * 14];
            const float* p1 = p0 + 14;
            #pragma unroll
            for (int w = 0; w < 7; ++w) {
                const float4 q = wf[w];
                acc += p0[2 * w] * q.x + p0[2 * w + 1] * q.y
                     + p1[2 * w] * q.z + p1[2 * w + 1] * q.w;
            }
        }
        out[(size_t)b * 336 + idx] = sigmoidf_(acc + tb[idx]);
    }
}

extern "C" void kernel_launch(void* const* d_in, const int* in_sizes, int n_in,
                              void* d_out, int out_size, void* d_ws, size_t ws_size,
                              hipStream_t stream) {
    const float* x  = (const float*)d_in[0];
    const float* cw = (const float*)d_in[1];
    const float* cb = (const float*)d_in[2];
    const float* tw = (const float*)d_in[3];
    const float* tb = (const float*)d_in[4];
    float* out = (float*)d_out;

    const int B = in_sizes[0] / 3072;   // 4096
    const size_t need = (size_t)TWBYTES + (size_t)B * POOL_BYTES;   // ~83 MB
    if (ws_size >= need) {
        ushort* tw2    = (ushort*)d_ws;
        ushort* pool16 = (ushort*)((char*)d_ws + TWBYTES);
        prep_tw<<<(NTW + 255) / 256, 256, 0, stream>>>(tw, tw2);
        conv_pool_kernel<<<B, BLOCK, 0, stream>>>(x, cw, cb, pool16, B);
        tree_kernel<<<(B / 64) * 21, 64, 0, stream>>>(pool16, tw2, tb, out, B);
    } else {
        tree_backbone_legacy<<<B, BLOCK, 0, stream>>>(x, cw, cb, tw, tb, out, B);
    }
}

// Round 9
// 221.398 us; speedup vs baseline: 1.6360x; 1.5244x over previous
//
#include <hip/hip_runtime.h>
#include <hip/hip_fp16.h>
#include <math.h>

// TreeBackbone — round 9 = round 8 with ONE fix: h2 must be __fp16-based
// (cvt_pkrtz / fdot2 builtins use __fp16 ext_vector(2) on this toolchain).
//
//  conv: thread=(c,pq) owns one 64B pool chunk; weights in REGISTERS (7 b128
//        once per thread); results packed f16 in regs (cvt_pkrtz), stored
//        DIRECTLY to global -> no LDS staging/flush; LDS 18.9KB.
//  tree: f16 + v_dot2_f32_f16 (1 instr / 2 MAC, no unpack); 4-way f-split
//        (256-thr blocks, occ 12.6%->~60%); stride-17 LDS reduce; XCD swizzle.

#define NTW   (21 * 15 * 16 * 32)        // f16 weights, layout [gh][f][o][32]
#define TWBYTES (NTW * 2)
#define POOL_HALF 10080                  // per image: 315 chunks * 32 halfs
#define POOL_BYTES (POOL_HALF * 2)

typedef __fp16 h2 __attribute__((ext_vector_type(2)));   // FIX: __fp16 not _Float16
union HU { unsigned u; h2 v; };

#if defined(__has_builtin)
#if __has_builtin(__builtin_amdgcn_fdot2)
#define HAVE_FDOT2 1
#endif
#endif

__device__ __forceinline__ float sigmoidf_(float v) {
    return 1.0f / (1.0f + __expf(-v));
}
__device__ __forceinline__ unsigned pk2(float a, float b) {
    HU t; t.v = __builtin_amdgcn_cvt_pkrtz(a, b); return t.u;
}
__device__ __forceinline__ h2 as_h2(unsigned x) { HU t; t.u = x; return t.v; }

// ---- prep: tw fp32 (o,f,g,h,w,i,j) -> f16 [gh][f][o][32], e = i*14+2w+j ----
__global__ __launch_bounds__(256) void prep_tw(
    const float* __restrict__ tw, __half* __restrict__ tw2)
{
    int i = blockIdx.x * 256 + threadIdx.x;
    if (i >= NTW) return;
    const int e   = i & 31;
    const int o   = (i >> 5) & 15;
    const int fgh = i >> 9;
    const int f   = fgh % 15, gh = fgh / 15;
    const int g   = gh / 7,  h  = gh % 7;
    float v = 0.f;
    if (e < 28) {
        const int i2 = e / 14, rem = e % 14, w = rem >> 1, j = rem & 1;
        v = tw[o * 8820 + f * 588 + g * 196 + h * 28 + w * 4 + i2 * 2 + j];
    }
    tw2[i] = __float2half(v);
}

// ---- conv core: weights from register array, outputs to register array ----
template<int H>
__device__ __forceinline__ void conv_half_reg(
    const float* sx,           // s_x + g*1152 : [32 phys rows][36]
    const float (&w)[28],      // conv weights in VGPRs
    float cbias, int py,
    float (&out7)[7])          // pooled+sigmoid, px = 7H..7H+6
{
    float aA[14], aB[14];
    #pragma unroll
    for (int d = 0; d < 14; ++d) { aA[d] = 0.f; aB[d] = 0.f; }
    #pragma unroll
    for (int dr = 0; dr < 6; ++dr) {
        const float* rp = sx + (((dr & 1) << 4) + py + (dr >> 1)) * 36 + 12 * H;
        float f[20];
        #pragma unroll
        for (int k = 0; k < 5; ++k)
            *(float4*)&f[4 * k] = *(const float4*)&rp[4 * k];
        if (dr <= 4) {
            #pragma unroll
            for (int kx = 0; kx < 5; ++kx) {
                const float wv = w[dr * 5 + kx];
                #pragma unroll
                for (int d = 0; d < 14; ++d) aA[d] += f[d + kx + 2 * H] * wv;
            }
        }
        if (dr >= 1) {
            #pragma unroll
            for (int kx = 0; kx < 5; ++kx) {
                const float wv = w[(dr - 1) * 5 + kx];
                #pragma unroll
                for (int d = 0; d < 14; ++d) aB[d] += f[d + kx + 2 * H] * wv;
            }
        }
    }
    #pragma unroll
    for (int p = 0; p < 7; ++p) {
        float m = fmaxf(fmaxf(aA[2 * p], aA[2 * p + 1]),
                        fmaxf(aB[2 * p], aB[2 * p + 1]));
        out7[p] = sigmoidf_(m + cbias);
    }
}

// ---- kernel A: conv + pool + sigmoid -> f16 pool chunks direct to global ----
__global__ __launch_bounds__(320) void conv_pool_kernel(
    const float* __restrict__ x,    // (B,3,32,32)
    const float* __restrict__ cw,   // (45,25)
    const float* __restrict__ cb,   // (45,)
    __half* __restrict__ pool16,    // (B, 10080) f16
    int B)
{
    __shared__ float s_x[3 * 32 * 36];   // 13824 B interleaved rows
    __shared__ float s_cw[45 * 28];      // 5040 B (rows padded to 28: 16B-aligned)
    __shared__ float s_cb[45];

    const int b = blockIdx.x;
    if (b >= B) return;
    const int t = threadIdx.x;

    const float4* xs = (const float4*)(x + (size_t)b * 3072);
    for (int i = t; i < 768; i += 320) {
        const float4 v = xs[i];
        const int g = i >> 8, rem = i & 255, r = rem >> 3, q = rem & 7;
        const int p = ((r & 1) << 4) + (r >> 1);
        *(float4*)&s_x[(g * 32 + p) * 36 + q * 4] = v;
    }
    for (int i = t; i < 1125; i += 320) s_cw[(i / 25) * 28 + (i % 25)] = cw[i];
    if (t < 45) s_cb[t] = cb[t];
    __syncthreads();

    if (t >= 315) return;
    const int c = t / 7, pq = t % 7, g = c / 15;

    float w[28];
    #pragma unroll
    for (int k = 0; k < 7; ++k)
        *(float4*)&w[4 * k] = *(const float4*)&s_cw[c * 28 + 4 * k];
    const float cbias = s_cb[c];
    const float* sx = s_x + g * 1152;

    // vals[delta*2+H][p] ; chunk element e = delta*14 + 7H + p
    float vals[4][7];
    {
        const int py = 2 * pq;
        conv_half_reg<0>(sx, w, cbias, py, vals[0]);
        conv_half_reg<1>(sx, w, cbias, py, vals[1]);
    }
    {
        const int py = 2 * pq + 1;
        conv_half_reg<0>(sx, w, cbias, py, vals[2]);
        conv_half_reg<1>(sx, w, cbias, py, vals[3]);
    }

    unsigned u[16];
    #pragma unroll
    for (int m = 0; m < 14; ++m) {
        const int e0 = 2 * m, e1 = 2 * m + 1;
        u[m] = pk2(vals[e0 / 7][e0 % 7], vals[e1 / 7][e1 % 7]);
    }
    u[14] = 0u; u[15] = 0u;

    uint4* gdst = (uint4*)(pool16 + (size_t)b * POOL_HALF + (c * 7 + pq) * 32);
    gdst[0] = make_uint4(u[0],  u[1],  u[2],  u[3]);
    gdst[1] = make_uint4(u[4],  u[5],  u[6],  u[7]);
    gdst[2] = make_uint4(u[8],  u[9],  u[10], u[11]);
    gdst[3] = make_uint4(u[12], u[13], u[14], u[15]);
}

// ---- kernel B: tree, 256 thr = 64 images x 4 f-groups, dot2 MACs ----
__global__ __launch_bounds__(256) void tree_kernel(
    const __half* __restrict__ pool16,  // (B, 10080)
    const __half* __restrict__ tw2,     // [gh][f][o][32]
    const float* __restrict__ tb,       // (336,)
    float* __restrict__ out,            // (B,336)
    int B, int nblk)
{
    __shared__ float s_red[256 * 17];

    // XCD swizzle: co-locate a tile's 21 gh-blocks on one XCD (blk%8 -> XCD)
    const int cpx = nblk / 8;                         // 1344/8 = 168
    const int sid = (blockIdx.x % 8) * cpx + blockIdx.x / 8;
    const int gh = sid % 21, tile = sid / 21;
    const int g = gh / 7, h = gh % 7;

    const int t  = threadIdx.x;
    const int bl = t & 63, fg = t >> 6;               // image lane, f-group
    const int b  = tile * 64 + bl;
    if (b >= B) return;

    const int f0 = fg * 4;
    const int nf = (fg < 3) ? 4 : 3;

    float acc[16];
    #pragma unroll
    for (int o = 0; o < 16; ++o) acc[o] = 0.f;

    #pragma unroll 1
    for (int fi = 0; fi < nf; ++fi) {
        const int f = f0 + fi;
        const uint4* pc = (const uint4*)(pool16 + (size_t)b * POOL_HALF
                                         + ((g * 15 + f) * 7 + h) * 32);
        const uint4* wc = (const uint4*)(tw2 + (size_t)((gh * 15 + f) * 16) * 32);
        uint4 pu[4];
        #pragma unroll
        for (int k = 0; k < 4; ++k) pu[k] = pc[k];
        #pragma unroll
        for (int o = 0; o < 16; ++o) {
            #pragma unroll
            for (int k = 0; k < 4; ++k) {
                const uint4 wu = wc[o * 4 + k];
#ifdef HAVE_FDOT2
                acc[o] = __builtin_amdgcn_fdot2(as_h2(pu[k].x), as_h2(wu.x), acc[o], false);
                acc[o] = __builtin_amdgcn_fdot2(as_h2(pu[k].y), as_h2(wu.y), acc[o], false);
                acc[o] = __builtin_amdgcn_fdot2(as_h2(pu[k].z), as_h2(wu.z), acc[o], false);
                acc[o] = __builtin_amdgcn_fdot2(as_h2(pu[k].w), as_h2(wu.w), acc[o], false);
#else
                const unsigned pw[4] = {pu[k].x, pu[k].y, pu[k].z, pu[k].w};
                const unsigned ww[4] = {wu.x, wu.y, wu.z, wu.w};
                #pragma unroll
                for (int q = 0; q < 4; ++q) {
                    acc[o] += __half2float(__ushort_as_half((ushort)(pw[q] & 0xffff)))
                            * __half2float(__ushort_as_half((ushort)(ww[q] & 0xffff)));
                    acc[o] += __half2float(__ushort_as_half((ushort)(pw[q] >> 16)))
                            * __half2float(__ushort_as_half((ushort)(ww[q] >> 16)));
                }
#endif
            }
        }
    }

    #pragma unroll
    for (int o = 0; o < 16; ++o) s_red[t * 17 + o] = acc[o];
    __syncthreads();

    // final: t = (og 0..3, bl 0..63); each sums 4 f-groups for 4 'o'
    const int og = t >> 6;
    #pragma unroll
    for (int m = 0; m < 4; ++m) {
        const int o = og * 4 + m;
        float a = s_red[(0 * 64 + bl) * 17 + o] + s_red[(1 * 64 + bl) * 17 + o]
                + s_red[(2 * 64 + bl) * 17 + o] + s_red[(3 * 64 + bl) * 17 + o];
        const int idx = o * 21 + gh;
        out[(size_t)b * 336 + idx] = sigmoidf_(a + tb[idx]);
    }
}

// ---- fallback: round-2 fused kernel verbatim (fp32, known-good) ----
__global__ __launch_bounds__(256) void tree_backbone_legacy(
    const float* __restrict__ x, const float* __restrict__ cw,
    const float* __restrict__ cb, const float* __restrict__ tw,
    const float* __restrict__ tb, float* __restrict__ out, int B)
{
    __shared__ float s_x[3 * 32 * 36];
    __shared__ float s_cwl[45 * 25];
    __shared__ float s_cb[45];
    __shared__ float s_pool[45][197];

    const int b = blockIdx.x;
    if (b >= B) return;
    const int t = threadIdx.x;

    const float4* xs = (const float4*)(x + (size_t)b * 3072);
    for (int i = t; i < 768; i += 256) {
        const float4 v = xs[i];
        const int g = i >> 8, rem = i & 255, r = rem >> 3, q = rem & 7;
        const int p = ((r & 1) << 4) + (r >> 1);
        *(float4*)&s_x[(g * 32 + p) * 36 + q * 4] = v;
    }
    for (int i = t; i < 1125; i += 256) s_cwl[i] = cw[i];
    if (t < 45) s_cb[t] = cb[t];
    __syncthreads();

    for (int task = t; task < 1260; task += 256) {
        const int h  = (task >= 630) ? 1 : 0;
        const int tt = task - 630 * h;
        const int c  = tt / 14;
        const int py = tt - c * 14;
        const int g  = c / 15;
        float aA[14], aB[14];
        #pragma unroll
        for (int d = 0; d < 14; ++d) { aA[d] = 0.f; aB[d] = 0.f; }
        #pragma unroll
        for (int dr = 0; dr < 6; ++dr) {
            const float* rp = s_x + (g * 32 + ((dr & 1) << 4) + py + (dr >> 1)) * 36 + 12 * h;
            float f[20];
            #pragma unroll
            for (int k = 0; k < 5; ++k)
                *(float4*)&f[4 * k] = *(const float4*)&rp[4 * k];
            if (dr <= 4)
                #pragma unroll
                for (int kx = 0; kx < 5; ++kx) {
                    const float w = s_cwl[c * 25 + dr * 5 + kx];
                    #pragma unroll
                    for (int d = 0; d < 14; ++d) aA[d] += f[d + kx + 2 * h] * w;
                }
            if (dr >= 1)
                #pragma unroll
                for (int kx = 0; kx < 5; ++kx) {
                    const float w = s_cwl[c * 25 + (dr - 1) * 5 + kx];
                    #pragma unroll
                    for (int d = 0; d < 14; ++d) aB[d] += f[d + kx + 2 * h] * w;
                }
        }
        float* dst = &s_pool[c][py * 14 + 7 * h];
        #pragma unroll
        for (int p = 0; p < 7; ++p) {
            float m = fmaxf(fmaxf(aA[2 * p], aA[2 * p + 1]),
                            fmaxf(aB[2 * p], aB[2 * p + 1]));
            dst[p] = sigmoidf_(m + s_cb[c]);
        }
    }
    __syncthreads();

    for (int idx = t; idx < 336; idx += 256) {
        const int o  = idx / 21;
        const int r2 = idx - o * 21;
        const int g  = r2 / 7;
        const int hh = r2 - g * 7;
        const float* wp = tw + o * 8820 + g * 196 + hh * 28;
        float acc = 0.0f;
        #pragma unroll 1
        for (int f = 0; f < 15; ++f) {
            const float4* wf = (const float4*)(wp + f * 588);
            const float* p0 = &s_pool[g * 15 + f][(2 * hh) * 14];
            const float* p1 = p0 + 14;
            #pragma unroll
            for (int w = 0; w < 7; ++w) {
                const float4 q = wf[w];
                acc += p0[2 * w] * q.x + p0[2 * w + 1] * q.y
                     + p1[2 * w] * q.z + p1[2 * w + 1] * q.w;
            }
        }
        out[(size_t)b * 336 + idx] = sigmoidf_(acc + tb[idx]);
    }
}

extern "C" void kernel_launch(void* const* d_in, const int* in_sizes, int n_in,
                              void* d_out, int out_size, void* d_ws, size_t ws_size,
                              hipStream_t stream) {
    const float* x  = (const float*)d_in[0];
    const float* cw = (const float*)d_in[1];
    const float* cb = (const float*)d_in[2];
    const float* tw = (const float*)d_in[3];
    const float* tb = (const float*)d_in[4];
    float* out = (float*)d_out;

    const int B = in_sizes[0] / 3072;   // 4096
    const size_t need = (size_t)TWBYTES + (size_t)B * POOL_BYTES;   // ~83 MB
    if (ws_size >= need) {
        __half* tw2    = (__half*)d_ws;
        __half* pool16 = (__half*)((char*)d_ws + TWBYTES);
        const int nblk = (B / 64) * 21;
        prep_tw<<<(NTW + 255) / 256, 256, 0, stream>>>(tw, tw2);
        conv_pool_kernel<<<B, 320, 0, stream>>>(x, cw, cb, pool16, B);
        tree_kernel<<<nblk, 256, 0, stream>>>(pool16, tw2, tb, out, B, nblk);
    } else {
        tree_backbone_legacy<<<B, 256, 0, stream>>>(x, cw, cb, tw, tb, out, B);
    }
}

// Round 10
// 193.401 us; speedup vs baseline: 1.8728x; 1.1448x over previous
//
#include <hip/hip_runtime.h>
#include <hip/hip_fp16.h>
#include <math.h>

// TreeBackbone — round 10. Tree/prep kernels = round 9 verbatim (verified fast).
// Conv rebuilt on packed f16 math:
//   acc[d] = __half2 {conv row 2py, conv row 2py+1} at col d -> v_pk_fma_f16
//   halves the conv VALU stream (the measured bottleneck: latency-bound fp32).
//   Input staged as vertical h2 pairs, two parities (s_va even, s_vb odd),
//   XOR-swizzled 16B blocks (write & read same involution).
//   Pool -> LDS chunks [c][pq][32] -> coalesced uint4 flush (r7 pattern).

#define NTW   (21 * 15 * 16 * 32)        // f16 weights, layout [gh][f][o][32]
#define TWBYTES (NTW * 2)
#define POOL_HALF 10080                  // per image: 315 chunks * 32 halfs
#define POOL_BYTES (POOL_HALF * 2)

typedef __fp16 h2v __attribute__((ext_vector_type(2)));
union HU { unsigned u; h2v v; };

#if defined(__has_builtin)
#if __has_builtin(__builtin_amdgcn_fdot2)
#define HAVE_FDOT2 1
#endif
#endif

__device__ __forceinline__ float sigmoidf_(float v) {
    return 1.0f / (1.0f + __expf(-v));
}
__device__ __forceinline__ h2v as_h2(unsigned x) { HU t; t.u = x; return t.v; }
__device__ __forceinline__ unsigned packh2(float lo, float hi) {
    __half2 h = __halves2half2(__float2half_rn(lo), __float2half_rn(hi));
    return *reinterpret_cast<unsigned*>(&h);
}

// ---- prep: tw fp32 (o,f,g,h,w,i,j) -> f16 [gh][f][o][32], e = i*14+2w+j ----
__global__ __launch_bounds__(256) void prep_tw(
    const float* __restrict__ tw, __half* __restrict__ tw2)
{
    int i = blockIdx.x * 256 + threadIdx.x;
    if (i >= NTW) return;
    const int e   = i & 31;
    const int o   = (i >> 5) & 15;
    const int fgh = i >> 9;
    const int f   = fgh % 15, gh = fgh / 15;
    const int g   = gh / 7,  h  = gh % 7;
    float v = 0.f;
    if (e < 28) {
        const int i2 = e / 14, rem = e % 14, w = rem >> 1, j = rem & 1;
        v = tw[o * 8820 + f * 588 + g * 196 + h * 28 + w * 4 + i2 * 2 + j];
    }
    tw2[i] = __float2half(v);
}

// ---- kernel A: packed-f16 conv + pool + sigmoid -> f16 pool chunks ----
__global__ __launch_bounds__(320) void conv_pool_kernel(
    const float* __restrict__ x,    // (B,3,32,32)
    const float* __restrict__ cw,   // (45,25)
    const float* __restrict__ cb,   // (45,)
    __half* __restrict__ pool16,    // (B, 10080) f16
    int B)
{
    __shared__ __align__(16) unsigned s_va[3 * 16 * 32];  // pairs (2rp,2rp+1), swizzled
    __shared__ __align__(16) unsigned s_vb[3 * 16 * 32];  // pairs (2rp+1,2rp+2)
    __shared__ unsigned s_cw2[45 * 25];                    // f16 dup-halves weights
    __shared__ float    s_cb[45];
    __shared__ __align__(16) __half s_p16[POOL_HALF];      // pool chunks [c][pq][32]

    const int b = blockIdx.x;
    if (b >= B) return;
    const int t = threadIdx.x;
    const float* xb = x + (size_t)b * 3072;

    // stage even-parity vertical pairs: 3g * 16rp * 8 quads
    for (int i = t; i < 384; i += 320) {
        const int g = i >> 7, rem = i & 127, rp = rem >> 3, c4 = rem & 7;
        const float4 r0 = *(const float4*)&xb[(g * 32 + 2 * rp) * 32 + c4 * 4];
        const float4 r1 = *(const float4*)&xb[(g * 32 + 2 * rp + 1) * 32 + c4 * 4];
        uint4 q;
        q.x = packh2(r0.x, r1.x); q.y = packh2(r0.y, r1.y);
        q.z = packh2(r0.z, r1.z); q.w = packh2(r0.w, r1.w);
        *(uint4*)&s_va[(g * 16 + rp) * 32 + ((c4 ^ (rp & 7)) << 2)] = q;
    }
    // stage odd-parity vertical pairs: 3g * 15rp * 8 quads
    for (int i = t; i < 360; i += 320) {
        const int g = i / 120, rem = i % 120, rp = rem >> 3, c4 = rem & 7;
        const float4 r0 = *(const float4*)&xb[(g * 32 + 2 * rp + 1) * 32 + c4 * 4];
        const float4 r1 = *(const float4*)&xb[(g * 32 + 2 * rp + 2) * 32 + c4 * 4];
        uint4 q;
        q.x = packh2(r0.x, r1.x); q.y = packh2(r0.y, r1.y);
        q.z = packh2(r0.z, r1.z); q.w = packh2(r0.w, r1.w);
        *(uint4*)&s_vb[(g * 16 + rp) * 32 + ((c4 ^ (rp & 7)) << 2)] = q;
    }
    // weights: f16 duplicated into both halves
    for (int i = t; i < 1125; i += 320) {
        const unsigned hu = __half_as_ushort(__float2half_rn(cw[i]));
        s_cw2[i] = hu | (hu << 16);
    }
    if (t < 45) s_cb[t] = cb[t];
    for (int i = t; i < 315; i += 320)      // zero chunk pads (tree reads all 32)
        *(uint2*)&s_p16[i * 32 + 28] = make_uint2(0u, 0u);
    __syncthreads();

    // ---- tasks: (c, py) -> 28 conv cols x 2 conv rows packed; pool 14 values ----
    #pragma unroll 1
    for (int task = t; task < 630; task += 320) {
        const int c = task / 14, py = task % 14, g = c / 15;

        __half2 acc[28];
        #pragma unroll
        for (int d = 0; d < 28; ++d) acc[d] = __float2half2_rn(0.f);

        #pragma unroll
        for (int ky = 0; ky < 5; ++ky) {
            const int r0 = 2 * py + ky;           // top conv-input row of the pair
            const int rp = r0 >> 1;
            const unsigned* src = (r0 & 1) ? &s_vb[(g * 16 + rp) * 32]
                                           : &s_va[(g * 16 + rp) * 32];
            const int sw = rp & 7;
            unsigned row[32];
            #pragma unroll
            for (int bk = 0; bk < 8; ++bk)
                *(uint4*)&row[bk * 4] = *(const uint4*)&src[(bk ^ sw) << 2];

            const unsigned* wrow = &s_cw2[c * 25 + ky * 5];
            #pragma unroll
            for (int kx = 0; kx < 5; ++kx) {
                const __half2 w2 = *reinterpret_cast<const __half2*>(&wrow[kx]);
                #pragma unroll
                for (int d = 0; d < 28; ++d) {
                    unsigned ru = row[d + kx];
                    acc[d] = __hfma2(*reinterpret_cast<__half2*>(&ru), w2, acc[d]);
                }
            }
        }

        // pool 2x2 (cols 2px,2px+1 x both packed rows) + bias + sigmoid
        const float cbias = s_cb[c];
        __half* dst = &s_p16[(c * 7 + (py >> 1)) * 32 + (py & 1) * 14];
        #pragma unroll
        for (int px = 0; px < 14; px += 2) {   // write pairs -> 4B stores
            float m0, m1;
            {
                const __half2 a = acc[2 * px], bb = acc[2 * px + 1];
                m0 = fmaxf(fmaxf(__low2float(a), __high2float(a)),
                           fmaxf(__low2float(bb), __high2float(bb)));
            }
            {
                const __half2 a = acc[2 * px + 2], bb = acc[2 * px + 3];
                m1 = fmaxf(fmaxf(__low2float(a), __high2float(a)),
                           fmaxf(__low2float(bb), __high2float(bb)));
            }
            const __half2 pv = __halves2half2(
                __float2half_rn(sigmoidf_(m0 + cbias)),
                __float2half_rn(sigmoidf_(m1 + cbias)));
            *reinterpret_cast<__half2*>(dst + px) = pv;
        }
    }
    __syncthreads();

    // coalesced flush: 1260 uint4
    const uint4* src4 = (const uint4*)s_p16;
    uint4* dst4 = (uint4*)(pool16 + (size_t)b * POOL_HALF);
    for (int i = t; i < 1260; i += 320) dst4[i] = src4[i];
}

// ---- kernel B: tree, 256 thr = 64 images x 4 f-groups, dot2 MACs (r9 verbatim) ----
__global__ __launch_bounds__(256) void tree_kernel(
    const __half* __restrict__ pool16,  // (B, 10080)
    const __half* __restrict__ tw2,     // [gh][f][o][32]
    const float* __restrict__ tb,       // (336,)
    float* __restrict__ out,            // (B,336)
    int B, int nblk)
{
    __shared__ float s_red[256 * 17];

    const int cpx = nblk / 8;
    const int sid = (blockIdx.x % 8) * cpx + blockIdx.x / 8;
    const int gh = sid % 21, tile = sid / 21;
    const int g = gh / 7, h = gh % 7;

    const int t  = threadIdx.x;
    const int bl = t & 63, fg = t >> 6;
    const int b  = tile * 64 + bl;
    if (b >= B) return;

    const int f0 = fg * 4;
    const int nf = (fg < 3) ? 4 : 3;

    float acc[16];
    #pragma unroll
    for (int o = 0; o < 16; ++o) acc[o] = 0.f;

    #pragma unroll 1
    for (int fi = 0; fi < nf; ++fi) {
        const int f = f0 + fi;
        const uint4* pc = (const uint4*)(pool16 + (size_t)b * POOL_HALF
                                         + ((g * 15 + f) * 7 + h) * 32);
        const uint4* wc = (const uint4*)(tw2 + (size_t)((gh * 15 + f) * 16) * 32);
        uint4 pu[4];
        #pragma unroll
        for (int k = 0; k < 4; ++k) pu[k] = pc[k];
        #pragma unroll
        for (int o = 0; o < 16; ++o) {
            #pragma unroll
            for (int k = 0; k < 4; ++k) {
                const uint4 wu = wc[o * 4 + k];
#ifdef HAVE_FDOT2
                acc[o] = __builtin_amdgcn_fdot2(as_h2(pu[k].x), as_h2(wu.x), acc[o], false);
                acc[o] = __builtin_amdgcn_fdot2(as_h2(pu[k].y), as_h2(wu.y), acc[o], false);
                acc[o] = __builtin_amdgcn_fdot2(as_h2(pu[k].z), as_h2(wu.z), acc[o], false);
                acc[o] = __builtin_amdgcn_fdot2(as_h2(pu[k].w), as_h2(wu.w), acc[o], false);
#else
                const unsigned pw[4] = {pu[k].x, pu[k].y, pu[k].z, pu[k].w};
                const unsigned ww[4] = {wu.x, wu.y, wu.z, wu.w};
                #pragma unroll
                for (int q = 0; q < 4; ++q) {
                    acc[o] += __half2float(__ushort_as_half((ushort)(pw[q] & 0xffff)))
                            * __half2float(__ushort_as_half((ushort)(ww[q] & 0xffff)));
                    acc[o] += __half2float(__ushort_as_half((ushort)(pw[q] >> 16)))
                            * __half2float(__ushort_as_half((ushort)(ww[q] >> 16)));
                }
#endif
            }
        }
    }

    #pragma unroll
    for (int o = 0; o < 16; ++o) s_red[t * 17 + o] = acc[o];
    __syncthreads();

    const int og = t >> 6;
    #pragma unroll
    for (int m = 0; m < 4; ++m) {
        const int o = og * 4 + m;
        float a = s_red[(0 * 64 + bl) * 17 + o] + s_red[(1 * 64 + bl) * 17 + o]
                + s_red[(2 * 64 + bl) * 17 + o] + s_red[(3 * 64 + bl) * 17 + o];
        const int idx = o * 21 + gh;
        out[(size_t)b * 336 + idx] = sigmoidf_(a + tb[idx]);
    }
}

// ---- fallback: round-2 fused kernel verbatim (fp32, known-good) ----
__global__ __launch_bounds__(256) void tree_backbone_legacy(
    const float* __restrict__ x, const float* __restrict__ cw,
    const float* __restrict__ cb, const float* __restrict__ tw,
    const float* __restrict__ tb, float* __restrict__ out, int B)
{
    __shared__ float s_x[3 * 32 * 36];
    __shared__ float s_cwl[45 * 25];
    __shared__ float s_cb[45];
    __shared__ float s_pool[45][197];

    const int b = blockIdx.x;
    if (b >= B) return;
    const int t = threadIdx.x;

    const float4* xs = (const float4*)(x + (size_t)b * 3072);
    for (int i = t; i < 768; i += 256) {
        const float4 v = xs[i];
        const int g = i >> 8, rem = i & 255, r = rem >> 3, q = rem & 7;
        const int p = ((r & 1) << 4) + (r >> 1);
        *(float4*)&s_x[(g * 32 + p) * 36 + q * 4] = v;
    }
    for (int i = t; i < 1125; i += 256) s_cwl[i] = cw[i];
    if (t < 45) s_cb[t] = cb[t];
    __syncthreads();

    for (int task = t; task < 1260; task += 256) {
        const int h  = (task >= 630) ? 1 : 0;
        const int tt = task - 630 * h;
        const int c  = tt / 14;
        const int py = tt - c * 14;
        const int g  = c / 15;
        float aA[14], aB[14];
        #pragma unroll
        for (int d = 0; d < 14; ++d) { aA[d] = 0.f; aB[d] = 0.f; }
        #pragma unroll
        for (int dr = 0; dr < 6; ++dr) {
            const float* rp = s_x + (g * 32 + ((dr & 1) << 4) + py + (dr >> 1)) * 36 + 12 * h;
            float f[20];
            #pragma unroll
            for (int k = 0; k < 5; ++k)
                *(float4*)&f[4 * k] = *(const float4*)&rp[4 * k];
            if (dr <= 4)
                #pragma unroll
                for (int kx = 0; kx < 5; ++kx) {
                    const float w = s_cwl[c * 25 + dr * 5 + kx];
                    #pragma unroll
                    for (int d = 0; d < 14; ++d) aA[d] += f[d + kx + 2 * h] * w;
                }
            if (dr >= 1)
                #pragma unroll
                for (int kx = 0; kx < 5; ++kx) {
                    const float w = s_cwl[c * 25 + (dr - 1) * 5 + kx];
                    #pragma unroll
                    for (int d = 0; d < 14; ++d) aB[d] += f[d + kx + 2 * h] * w;
                }
        }
        float* dst = &s_pool[c][py * 14 + 7 * h];
        #pragma unroll
        for (int p = 0; p < 7; ++p) {
            float m = fmaxf(fmaxf(aA[2 * p], aA[2 * p + 1]),
                            fmaxf(aB[2 * p], aB[2 * p + 1]));
            dst[p] = sigmoidf_(m + s_cb[c]);
        }
    }
    __syncthreads();

    for (int idx = t; idx < 336; idx += 256) {
        const int o  = idx / 21;
        const int r2 = idx - o * 21;
        const int g  = r2 / 7;
        const int hh = r2 - g * 7;
        const float* wp = tw + o * 8820 + g * 196 + hh * 28;
        float acc = 0.0f;
        #pragma unroll 1
        for (int f = 0; f < 15; ++f) {
            const float4* wf = (const float4*)(wp + f * 588);
            const float* p0 = &s_pool[g * 15 + f][(2 * hh) * 14];
            const float* p1 = p0 + 14;
            #pragma unroll
            for (int w = 0; w < 7; ++w) {
                const float4 q = wf[w];
                acc += p0[2 * w] * q.x + p0[2 * w + 1] * q.y
                     + p1[2 * w] * q.z + p1[2 * w + 1] * q.w;
            }
        }
        out[(size_t)b * 336 + idx] = sigmoidf_(acc + tb[idx]);
    }
}

extern "C" void kernel_launch(void* const* d_in, const int* in_sizes, int n_in,
                              void* d_out, int out_size, void* d_ws, size_t ws_size,
                              hipStream_t stream) {
    const float* x  = (const float*)d_in[0];
    const float* cw = (const float*)d_in[1];
    const float* cb = (const float*)d_in[2];
    const float* tw = (const float*)d_in[3];
    const float* tb = (const float*)d_in[4];
    float* out = (float*)d_out;

    const int B = in_sizes[0] / 3072;   // 4096
    const size_t need = (size_t)TWBYTES + (size_t)B * POOL_BYTES;   // ~83 MB
    if (ws_size >= need) {
        __half* tw2    = (__half*)d_ws;
        __half* pool16 = (__half*)((char*)d_ws + TWBYTES);
        const int nblk = (B / 64) * 21;
        prep_tw<<<(NTW + 255) / 256, 256, 0, stream>>>(tw, tw2);
        conv_pool_kernel<<<B, 320, 0, stream>>>(x, cw, cb, pool16, B);
        tree_kernel<<<nblk, 256, 0, stream>>>(pool16, tw2, tb, out, B, nblk);
    } else {
        tree_backbone_legacy<<<B, 256, 0, stream>>>(x, cw, cb, tw, tb, out, B);
    }
}